// Round 5
// baseline (906.267 us; speedup 1.0000x reference)
//
#include <hip/hip_runtime.h>
#include <hip/hip_bf16.h>

#define N_ROWS   32768
#define DIM      256
#define DIM4     64
#define K_CODES  1024
#define INV_T    20.0f

#define ROWS_PER_BLK 32
#define CHUNK        32
#define NCHUNK       32     // K_CODES / CHUNK
#define ZS_STRIDE    260    // 256 + 4 pad (16B-aligned rows, odd granule stride)
#define ES_STRIDE    260

#define Q_OFF    0
#define LOSS_OFF 8388608
#define IDX_OFF  8388609
#define AVG_OFF  8421377

// ---- kernel 1: codebook squared norms, numpy-pairwise-exact fp32 ----
// np: s = P(x[0:128]) + P(x[128:256]);  P = 8-accumulator unrolled block,
// combined ((r0+r1)+(r2+r3))+((r4+r5)+(r6+r7)). Square rounded BEFORE add.
__global__ void vq_norms(const float* __restrict__ emb, float* __restrict__ ne) {
    int k = blockIdx.x * blockDim.x + threadIdx.x;
    if (k >= K_CODES) return;
    const float* row = emb + (size_t)k * DIM;
    float blk[2];
    #pragma unroll
    for (int b = 0; b < 2; ++b) {
        const float* x = row + b * 128;
        float r[8];
        #pragma unroll
        for (int j = 0; j < 8; ++j) r[j] = __fmul_rn(x[j], x[j]);
        for (int i = 8; i < 128; i += 8) {
            #pragma unroll
            for (int j = 0; j < 8; ++j)
                r[j] = __fadd_rn(r[j], __fmul_rn(x[i + j], x[i + j]));
        }
        float t01 = __fadd_rn(r[0], r[1]);
        float t23 = __fadd_rn(r[2], r[3]);
        float t45 = __fadd_rn(r[4], r[5]);
        float t67 = __fadd_rn(r[6], r[7]);
        blk[b] = __fadd_rn(__fadd_rn(t01, t23), __fadd_rn(t45, t67));
    }
    ne[k] = __fadd_rn(blk[0], blk[1]);
}

// ---- kernel 2: zero the accumulated outputs ----
__global__ void vq_init(float* __restrict__ out) {
    int i = blockIdx.x * blockDim.x + threadIdx.x;
    if (i == 0) out[LOSS_OFF] = 0.f;
    if (i < K_CODES) out[AVG_OFF + i] = 0.f;
}

// ---- kernel 3: fused distances/argmin/softmax/gather/losses ----
__global__ __launch_bounds__(256) void vq_main(
    const float4* __restrict__ z4,
    const float4* __restrict__ emb4,
    const float* __restrict__ ne,
    float* __restrict__ out)
{
    __shared__ float zs[ROWS_PER_BLK * ZS_STRIDE];
    __shared__ float es[CHUNK * ES_STRIDE];
    __shared__ float avg_lds[K_CODES];
    __shared__ float nzs[ROWS_PER_BLK];
    __shared__ int   bestIdx[ROWS_PER_BLK];
    __shared__ float redbuf[4];

    const int t  = threadIdx.x;
    const int n0 = blockIdx.x * ROWS_PER_BLK;
    const int c  = t & 31;   // code lane within chunk
    const int g  = t >> 5;   // row group 0..7 -> rows g*4 .. g*4+3

    #pragma unroll
    for (int i = 0; i < 4; ++i) avg_lds[i * 256 + t] = 0.f;

    // stage z tile: 32 rows x 64 float4 (coalesced)
    #pragma unroll
    for (int i = 0; i < 8; ++i) {
        int f = i * 256 + t;
        int r = f >> 6, d4 = f & 63;
        float4 v = z4[(size_t)(n0 + r) * DIM4 + d4];
        *reinterpret_cast<float4*>(&zs[r * ZS_STRIDE + d4 * 4]) = v;
    }
    __syncthreads();

    // ---- ||z||^2 per row, numpy-pairwise-exact (16 lanes/row) ----
    // lane j8 of block blk owns chain r[j8] over x[blk*128 + j8 + 8b], b=0..15.
    // xor-tree 1,2,4 reproduces ((r0+r1)+(r2+r3))+((r4+r5)+(r6+r7)) (adds are
    // commutative in RN, so shuffle pairing is bit-exact); xor 8 does B0+B1.
    {
        const int lane = t & 63;
        const int wv   = t >> 6;
        const int j8   = lane & 7;
        const int blk  = (lane >> 3) & 1;
        const int rsub = lane >> 4;
        #pragma unroll
        for (int p = 0; p < 2; ++p) {
            int row = p * 16 + wv * 4 + rsub;
            const float* x = &zs[row * ZS_STRIDE + blk * 128];
            float v0 = x[j8];
            float s = __fmul_rn(v0, v0);
            #pragma unroll
            for (int b = 1; b < 16; ++b) {
                float v = x[j8 + 8 * b];
                s = __fadd_rn(s, __fmul_rn(v, v));
            }
            s = __fadd_rn(s, __shfl_xor(s, 1));
            s = __fadd_rn(s, __shfl_xor(s, 2));
            s = __fadd_rn(s, __shfl_xor(s, 4));
            s = __fadd_rn(s, __shfl_xor(s, 8));   // B0 + B1
            if ((lane & 15) == 0) nzs[row] = s;
        }
    }
    // nzs visibility: covered by the chunk loop's first __syncthreads()

    float acc[NCHUNK][4];   // dot(z_row, e_code); fully unrolled => registers

    #pragma unroll
    for (int jc = 0; jc < NCHUNK; ++jc) {
        __syncthreads();
        #pragma unroll
        for (int i = 0; i < 8; ++i) {
            int f = i * 256 + t;
            int cr = f >> 6, d4 = f & 63;
            float4 v = emb4[(size_t)(jc * CHUNK + cr) * DIM4 + d4];
            *reinterpret_cast<float4*>(&es[cr * ES_STRIDE + d4 * 4]) = v;
        }
        __syncthreads();

        const float4* erow = reinterpret_cast<const float4*>(&es[c * ES_STRIDE]);
        const float4* zr0  = reinterpret_cast<const float4*>(&zs[(g * 4 + 0) * ZS_STRIDE]);
        const float4* zr1  = reinterpret_cast<const float4*>(&zs[(g * 4 + 1) * ZS_STRIDE]);
        const float4* zr2  = reinterpret_cast<const float4*>(&zs[(g * 4 + 2) * ZS_STRIDE]);
        const float4* zr3  = reinterpret_cast<const float4*>(&zs[(g * 4 + 3) * ZS_STRIDE]);

        // single sequential FMA chain per (row,code) in ascending d order —
        // matches BLAS sgemm rank-1-update accumulation (beta=0 start).
        float a0 = 0.f, a1 = 0.f, a2 = 0.f, a3 = 0.f;
        #pragma unroll 4
        for (int d4 = 0; d4 < DIM4; ++d4) {
            float4 e4 = erow[d4];
            float4 v0 = zr0[d4];
            float4 v1 = zr1[d4];
            float4 v2 = zr2[d4];
            float4 v3 = zr3[d4];
            a0 = __builtin_fmaf(v0.x, e4.x, a0);
            a0 = __builtin_fmaf(v0.y, e4.y, a0);
            a0 = __builtin_fmaf(v0.z, e4.z, a0);
            a0 = __builtin_fmaf(v0.w, e4.w, a0);
            a1 = __builtin_fmaf(v1.x, e4.x, a1);
            a1 = __builtin_fmaf(v1.y, e4.y, a1);
            a1 = __builtin_fmaf(v1.z, e4.z, a1);
            a1 = __builtin_fmaf(v1.w, e4.w, a1);
            a2 = __builtin_fmaf(v2.x, e4.x, a2);
            a2 = __builtin_fmaf(v2.y, e4.y, a2);
            a2 = __builtin_fmaf(v2.z, e4.z, a2);
            a2 = __builtin_fmaf(v2.w, e4.w, a2);
            a3 = __builtin_fmaf(v3.x, e4.x, a3);
            a3 = __builtin_fmaf(v3.y, e4.y, a3);
            a3 = __builtin_fmaf(v3.z, e4.z, a3);
            a3 = __builtin_fmaf(v3.w, e4.w, a3);
        }
        acc[jc][0] = a0; acc[jc][1] = a1; acc[jc][2] = a2; acc[jc][3] = a3;
    }

    // ---- distances exactly as np: d = RN( RN(nz + ne_k) - 2*dot ) ----
    float nzv[4];
    #pragma unroll
    for (int r = 0; r < 4; ++r) nzv[r] = nzs[g * 4 + r];

    #pragma unroll
    for (int jc = 0; jc < NCHUNK; ++jc) {
        float nv = ne[jc * CHUNK + c];
        #pragma unroll
        for (int r = 0; r < 4; ++r) {
            float S = __fadd_rn(nzv[r], nv);
            acc[jc][r] = __fsub_rn(S, 2.f * acc[jc][r]);   // 2*dot exact; single RN sub
        }
    }

    float pa[NCHUNK];
    #pragma unroll
    for (int jc = 0; jc < NCHUNK; ++jc) pa[jc] = 0.f;

    #pragma unroll
    for (int r = 0; r < 4; ++r) {
        // lane-local argmin (ascending code order; strict < keeps first index)
        float m = acc[0][r];
        int   bi = c;
        #pragma unroll
        for (int jc = 1; jc < NCHUNK; ++jc) {
            float v = acc[jc][r];
            if (v < m) { m = v; bi = jc * CHUNK + c; }
        }
        // 32-lane reduce; tie -> smaller index (np argmin first-occurrence)
        #pragma unroll
        for (int off = 16; off >= 1; off >>= 1) {
            float om = __shfl_xor(m, off);
            int   oi = __shfl_xor(bi, off);
            if (om < m || (om == m && oi < bi)) { m = om; bi = oi; }
        }
        // softmax(-d/T): p = exp((dmin - d)*INV_T) / sum
        float s = 0.f;
        #pragma unroll
        for (int jc = 0; jc < NCHUNK; ++jc) s += __expf((m - acc[jc][r]) * INV_T);
        #pragma unroll
        for (int off = 16; off >= 1; off >>= 1) s += __shfl_xor(s, off);
        float inv_s = 1.f / s;
        #pragma unroll
        for (int jc = 0; jc < NCHUNK; ++jc)
            pa[jc] += __expf((m - acc[jc][r]) * INV_T) * inv_s;
        if (c == 0) bestIdx[g * 4 + r] = bi;
    }

    #pragma unroll
    for (int jc = 0; jc < NCHUNK; ++jc)
        atomicAdd(&avg_lds[jc * CHUNK + c], pa[jc]);

    __syncthreads();

    #pragma unroll
    for (int i = 0; i < 4; ++i) {
        int k = i * 256 + t;
        atomicAdd(&out[AVG_OFF + k], avg_lds[k] * (1.0f / (float)N_ROWS));
    }

    if (t < ROWS_PER_BLK) out[IDX_OFF + n0 + t] = (float)bestIdx[t];

    // quantized output (gather emb[idx]) + fused vq loss
    float lpart = 0.f;
    #pragma unroll
    for (int i = 0; i < 8; ++i) {
        int f = i * 256 + t;
        int r = f >> 6, d4 = f & 63;
        int bi = bestIdx[r];
        float4 q = emb4[(size_t)bi * DIM4 + d4];
        reinterpret_cast<float4*>(out)[(size_t)(n0 + r) * DIM4 + d4] = q;
        float4 zz = *reinterpret_cast<const float4*>(&zs[r * ZS_STRIDE + d4 * 4]);
        float dx = q.x - zz.x, dy = q.y - zz.y, dz = q.z - zz.z, dw = q.w - zz.w;
        lpart += dx * dx + dy * dy + dz * dz + dw * dw;
    }
    #pragma unroll
    for (int off = 32; off >= 1; off >>= 1) lpart += __shfl_xor(lpart, off);
    int wid = t >> 6;
    if ((t & 63) == 0) redbuf[wid] = lpart;
    __syncthreads();
    if (t == 0) {
        float tot = redbuf[0] + redbuf[1] + redbuf[2] + redbuf[3];
        atomicAdd(&out[LOSS_OFF], tot * (1.25f / (float)(N_ROWS * DIM)));
    }
}

extern "C" void kernel_launch(void* const* d_in, const int* in_sizes, int n_in,
                              void* d_out, int out_size, void* d_ws, size_t ws_size,
                              hipStream_t stream) {
    const float* z   = (const float*)d_in[0];
    const float* emb = (const float*)d_in[1];
    float* out = (float*)d_out;
    float* ne  = (float*)d_ws;   // 1024 floats of scratch

    vq_norms<<<dim3(4), dim3(256), 0, stream>>>(emb, ne);
    vq_init<<<dim3(4), dim3(256), 0, stream>>>(out);
    vq_main<<<dim3(N_ROWS / ROWS_PER_BLK), dim3(256), 0, stream>>>(
        (const float4*)z, (const float4*)emb, ne, out);
}